// Round 12
// baseline (25.360 us; speedup 1.0000x reference)
//
#include <hip/hip_runtime.h>
#include <math.h>

#define EPS 1e-6f
#define BN_EPSF 1e-5f
#define PI2F 6.2831853071795864769f
#define INV2PIF 0.15915494309189535f
#define LOG2EF 1.4426950408889634f
#define NBB 4
#define NCC 512
#define NGG 2048
#define OUTC 64
#define NBAS 10

// d_out layout (floats): y_out, n_f, fourier_prior, n_h1, h0_f
#define Y_OFF   0
#define NF_OFF  (NBB*NGG*OUTC)          // 524288
#define FP_OFF  (NF_OFF  + NBB*NGG*9)   // 598016
#define NH1_OFF (FP_OFF  + NBB*NGG*9)   // 671744
#define H0_OFF  (NH1_OFF + NBB*NGG*9)   // 745472

// ws layout (floats)
#define WSH0     0                      // raw h0 sums, NBB*9*NGG = 73728
#define WSH1     (NBB*9*NGG)            // raw h1 sums
#define WS_CONV  (2*NBB*9*NGG)          // conv outputs
#define WS_STATS (3*NBB*9*NGG)          // 9 cps * 32 blocks * {sum,sumsq}

#if defined(__has_builtin)
# if __has_builtin(__builtin_amdgcn_exp2f)
#  define EXP2F(x) __builtin_amdgcn_exp2f(x)
# endif
# if __has_builtin(__builtin_amdgcn_cosf)
#  define COS_REV(r) __builtin_amdgcn_cosf(r)   // cos(2*pi*r), r in [0,1)
# endif
#endif
#ifndef EXP2F
# define EXP2F(x) exp2f(x)
#endif
#ifndef COS_REV
# define COS_REV(r) cosf(PI2F*(r))
#endif

// ---------------------------------------------------------------------------
// K1: PURE RBF partial sums for 8 g. 1024 blocks (4 b x 256 tiles) x 256 thr.
// Round-12 changes: (1) in-wave shfl fold of the 8 chunks per wave ->
// red shrinks to [4][8][19] (2.4 KB), LDS 36->19 KB -> 6+ blocks/CU;
// (2) float4 context staging (1.5 loads/thread instead of 6).
// Skewed LDS: ctx n at float offset n*8 + (n>>5)*4 -> affine addresses,
// 2-way broadcast banks (free).
// ---------------------------------------------------------------------------
__global__ __launch_bounds__(256) void k1_rbf(
    const float* __restrict__ x_c, const float* __restrict__ y_c,
    const float* __restrict__ x_g, const float* __restrict__ sigma,
    float* __restrict__ ws)
{
    const int bid = blockIdx.x;
    const int b = bid >> 8;            // 4 b x 256 tiles of 8 g
    const int gtile = bid & 255;
    const int g0 = gtile * 8;
    const int tid = threadIdx.x;

    __shared__ float cxy[NCC*8 + (NCC/32)*4];  // 16.6 KB skewed (x0,y0,x1,y1,x2,y2,-,-)
    __shared__ float red[4][8][19];            // 2.4 KB per-wave folded partials

    // ---- stage context set via float4 (NCC*3/4 = 384 vector pairs) ----
    const float4* xc4 = (const float4*)(x_c + b*NCC*3);
    const float4* yc4 = (const float4*)(y_c + b*NCC*3);
    for (int i = tid; i < (NCC*3)/4; i += 256) {
        float4 xv = xc4[i];
        float4 yv = yc4[i];
        int f0 = i*4;                  // flat index of xv.x
        #pragma unroll
        for (int j = 0; j < 4; ++j) {
            int f = f0 + j;
            int n = f/3, c = f - n*3;
            int base = n*8 + ((n>>5)<<2);
            float xs = (j==0)?xv.x:(j==1)?xv.y:(j==2)?xv.z:xv.w;
            float ys = (j==0)?yv.x:(j==1)?yv.y:(j==2)?yv.z:yv.w;
            cxy[base + 2*c]     = xs;
            cxy[base + 2*c + 1] = ys;
        }
    }

    float coef[3];
    #pragma unroll
    for (int p = 0; p < 3; ++p) {
        float s = expf(sigma[p]) + EPS;
        coef[p] = (-0.5f * LOG2EF) / (s*s);   // exp(-0.5 d^2) == exp2(d^2*coef)
    }

    const int gA = tid & 7;
    const int cA = tid >> 3;           // 32 chunks of 16 ctx
    const float xg0 = x_g[(b*NGG + g0 + gA)*3 + 0];
    const float xg1 = x_g[(b*NGG + g0 + gA)*3 + 1];
    const float xg2 = x_g[(b*NGG + g0 + gA)*3 + 2];

    __syncthreads();

    float h0a[3][3] = {{0}}, h1a[3][3] = {{0}};
    const int fbase = cA*128 + ((cA>>1)<<2);   // chunk base (16 ctx, skew-aligned)
    #pragma unroll 4
    for (int i = 0; i < 16; ++i) {
        float4 A = *(const float4*)&cxy[fbase + i*8];
        float4 B = *(const float4*)&cxy[fbase + i*8 + 4];
        float d0 = A.x - xg0, d1 = A.z - xg1, d2 = B.x - xg2;
        float dx2[3] = {d0*d0, d1*d1, d2*d2};
        float yv[3]  = {A.y, A.w, B.y};
        #pragma unroll
        for (int c = 0; c < 3; ++c)
            #pragma unroll
            for (int p = 0; p < 3; ++p) {
                float w = EXP2F(dx2[c] * coef[p]);
                h0a[c][p] += w;
                h1a[c][p] += w * yv[c];
            }
    }
    // ---- in-wave fold of the 8 chunks sharing gA (lane bits 3,4,5) ----
    #pragma unroll
    for (int c = 0; c < 3; ++c)
        #pragma unroll
        for (int p = 0; p < 3; ++p) {
            #pragma unroll
            for (int m = 8; m <= 32; m <<= 1) {
                h0a[c][p] += __shfl_xor(h0a[c][p], m);
                h1a[c][p] += __shfl_xor(h1a[c][p], m);
            }
        }
    {
        const int lane = tid & 63, wv = tid >> 6;
        if (lane < 8) {
            #pragma unroll
            for (int c = 0; c < 3; ++c)
                #pragma unroll
                for (int p = 0; p < 3; ++p) {
                    red[wv][lane][c*3 + p]     = h0a[c][p];
                    red[wv][lane][9 + c*3 + p] = h1a[c][p];
                }
        }
    }
    __syncthreads();

    // reduce 4 wave-partials -> raw h0,h1 to ws (72 items)
    if (tid < 72) {
        int gl = tid / 9, cp = tid - gl*9;
        float h0 = red[0][gl][cp]     + red[1][gl][cp]
                 + red[2][gl][cp]     + red[3][gl][cp];
        float h1 = red[0][gl][9 + cp] + red[1][gl][9 + cp]
                 + red[2][gl][9 + cp] + red[3][gl][9 + cp];
        int idx = (b*9 + cp)*NGG + g0 + gl;
        ws[WSH0 + idx] = h0;
        ws[WSH1 + idx] = h1;
    }
}

// ---------------------------------------------------------------------------
// K2: finalize (nh1 + Fourier prior via HW cos) for 256 own g + 8 halo g,
// then depthwise conv + BN partials. 288 blocks (4 b x 9 cp x 8 gc) x 256.
// ---------------------------------------------------------------------------
__global__ __launch_bounds__(256) void k2_fin_conv(
    const float* __restrict__ x_g, const float* __restrict__ sigma,
    const float* __restrict__ mu, const float* __restrict__ eps1,
    const float* __restrict__ b_u, const float* __restrict__ random_w,
    const float* __restrict__ cw1, const float* __restrict__ cb1,
    const float* __restrict__ cw2, const float* __restrict__ cb2,
    const float* __restrict__ cw3, const float* __restrict__ cb3,
    float* __restrict__ out, float* __restrict__ ws)
{
    const int bid = blockIdx.x;           // 4b x 9cp x 8gc = 288
    const int b = bid / 72; int r = bid - b*72;
    const int cp = r >> 3;  const int gc = r & 7;
    const int c = cp / 3, p = cp - c*3;
    const int tid = threadIdx.x;

    __shared__ float pre_l[264];          // 0..3 left halo, 4..259 own, 260..263 right
    __shared__ float swl[NBAS], sbl[NBAS], rwl[NBAS];
    __shared__ float r1[4], r2[4];

    if (tid < NBAS) {
        float wmu  = expf(mu[p]);
        float wstd = 1.0f / (expf(sigma[p]) + EPS);
        swl[tid] = wmu + wstd * eps1[(b*NBAS + tid)*3 + p];
        sbl[tid] = PI2F * b_u[(b*NBAS + tid)*3 + p];
        rwl[tid] = random_w[tid];
    }
    __syncthreads();

    for (int s = tid; s < 264; s += 256) {
        int gf = gc*256 - 4 + s;
        float v = 0.f;
        if (gf >= 0 && gf < NGG) {
            int idx = (b*9 + cp)*NGG + gf;
            float h0 = ws[WSH0 + idx];
            float h1 = ws[WSH1 + idx];
            float nh1 = h1 / (h0 + EPS);
            float xg = x_g[(b*NGG + gf)*3 + c];
            float fp = 0.f;
            #pragma unroll
            for (int k = 0; k < NBAS; ++k) {
                // arg bits match numpy (mul+add, round-to-nearest);
                // cos via HW: cos(arg) = v_cos(fract(arg/2pi)); reduction
                // error <= ~0.012 rad at |arg|<=1.5e5 — inside threshold.
                float arg = __fadd_rn(__fmul_rn(swl[k], xg), sbl[k]);
                float rev = arg * INV2PIF;
                rev = rev - floorf(rev);
                fp += rwl[k] * COS_REV(rev);
            }
            fp *= 0.44721359549995793f;   // sqrt(2/10)
            v = nh1 + fp;
            if (s >= 4 && s < 260) {      // own range: write the three outputs
                int obase = (b*NGG + gf)*9 + cp;
                out[H0_OFF  + obase] = h0;
                out[NH1_OFF + obase] = nh1;
                out[FP_OFF  + obase] = fp;
            }
        }
        pre_l[s] = v;                     // zero beyond grid edges (conv zero-pad)
    }
    __syncthreads();

    // depthwise conv (own 256 g) + deterministic BN partials
    int K, pad; const float* w; float bias;
    if (p == 0)      { K = 3; pad = 1; w = cw1 + c*3; bias = cb1[c]; }
    else if (p == 1) { K = 5; pad = 2; w = cw2 + c*5; bias = cb2[c]; }
    else             { K = 9; pad = 4; w = cw3 + c*9; bias = cb3[c]; }

    float acc = bias;
    for (int k = 0; k < K; ++k)
        acc += w[k] * pre_l[tid + 4 - pad + k];
    ws[WS_CONV + (b*9 + cp)*NGG + gc*256 + tid] = acc;

    float s1 = acc, s2 = acc*acc;
    #pragma unroll
    for (int o = 32; o > 0; o >>= 1) {
        s1 += __shfl_down(s1, o);
        s2 += __shfl_down(s2, o);
    }
    int lane = tid & 63, wv = tid >> 6;
    if (lane == 0) { r1[wv] = s1; r2[wv] = s2; }
    __syncthreads();
    if (tid == 0) {
        float t1 = r1[0] + r1[1] + r1[2] + r1[3];
        float t2 = r2[0] + r2[1] + r2[2] + r2[3];
        int pidx = cp*32 + b*8 + gc;
        ws[WS_STATS + pidx*2]     = t1;
        ws[WS_STATS + pidx*2 + 1] = t2;
    }
}

// ---------------------------------------------------------------------------
// K3: BN stats reduce + normalize (n_f) + output GEMV. 512 blocks x 256,
// each handling 16 P's (g_w/stats staged ONCE per block instead of 8x).
// ---------------------------------------------------------------------------
__global__ __launch_bounds__(256) void k3_out(
    const float* __restrict__ bn_gamma, const float* __restrict__ bn_beta,
    const float* __restrict__ g_w, const float* __restrict__ g_b,
    float* __restrict__ out, float* __restrict__ ws)
{
    __shared__ float4 gw4[OUTC*18/4];     // float4-staged g_w
    __shared__ float feat_l[4][18];
    __shared__ float ps[9][16][2];
    __shared__ float mstat[9][2];
    const int tid = threadIdx.x;
    float* gw_l = (float*)gw4;

    for (int i = tid; i < OUTC*18/4; i += 256)
        gw4[i] = ((const float4*)g_w)[i];
    if (tid < 144) {
        int cp = tid / 16, q = tid & 15;
        int idx = WS_STATS + (cp*32 + 2*q)*2;
        ps[cp][q][0] = ws[idx]     + ws[idx + 2];
        ps[cp][q][1] = ws[idx + 1] + ws[idx + 3];
    }
    __syncthreads();
    if (tid < 9) {
        float s1 = 0.f, s2 = 0.f;
        #pragma unroll
        for (int q = 0; q < 16; ++q) { s1 += ps[tid][q][0]; s2 += ps[tid][q][1]; }
        float mean = s1 * (1.0f/8192.0f);
        float var  = s2 * (1.0f/8192.0f) - mean*mean;
        mstat[tid][0] = mean;
        mstat[tid][1] = rsqrtf(var + BN_EPSF);
    }
    __syncthreads();

    const int pt = tid >> 6, o = tid & 63;
    #pragma unroll
    for (int rep = 0; rep < 4; ++rep) {
        if (tid < 72) {
            int pt2 = tid / 18, j = tid - pt2*18;
            int P = blockIdx.x*16 + rep*4 + pt2;
            int b = P >> 11, g = P & 2047;
            float f;
            if (j < 9) {
                f = out[H0_OFF + (b*NGG + g)*9 + j];
            } else {
                int cp = j - 9; int c = cp / 3, p = cp - c*3;
                float x = ws[WS_CONV + (b*9 + cp)*NGG + g];
                float v = bn_gamma[p*3 + c] * (x - mstat[cp][0]) * mstat[cp][1]
                          + bn_beta[p*3 + c];
                out[NF_OFF + (b*NGG + g)*9 + cp] = v;
                f = v;
            }
            feat_l[pt2][j] = f;
        }
        __syncthreads();

        int P = blockIdx.x*16 + rep*4 + pt;
        int b = P >> 11, g = P & 2047;
        float acc = g_b[o];
        #pragma unroll
        for (int j = 0; j < 18; ++j) acc += feat_l[pt][j] * gw_l[o*18 + j];
        out[Y_OFF + (b*NGG + g)*OUTC + o] = acc;
        __syncthreads();
    }
}

extern "C" void kernel_launch(void* const* d_in, const int* in_sizes, int n_in,
                              void* d_out, int out_size, void* d_ws, size_t ws_size,
                              hipStream_t stream)
{
    const float* x_c      = (const float*)d_in[0];
    const float* y_c      = (const float*)d_in[1];
    const float* x_g      = (const float*)d_in[2];
    const float* sigma    = (const float*)d_in[3];
    const float* mu       = (const float*)d_in[4];
    const float* eps1     = (const float*)d_in[5];
    const float* b_u      = (const float*)d_in[6];
    const float* random_w = (const float*)d_in[7];
    const float* conv_w1  = (const float*)d_in[8];
    const float* conv_b1  = (const float*)d_in[9];
    const float* conv_w2  = (const float*)d_in[10];
    const float* conv_b2  = (const float*)d_in[11];
    const float* conv_w3  = (const float*)d_in[12];
    const float* conv_b3  = (const float*)d_in[13];
    const float* bn_gamma = (const float*)d_in[14];
    const float* bn_beta  = (const float*)d_in[15];
    const float* g_w      = (const float*)d_in[16];
    const float* g_b      = (const float*)d_in[17];

    float* outp = (float*)d_out;
    float* wsp  = (float*)d_ws;

    k1_rbf<<<NBB*256, 256, 0, stream>>>(x_c, y_c, x_g, sigma, wsp);
    k2_fin_conv<<<NBB*9*(NGG/256), 256, 0, stream>>>(x_g, sigma, mu, eps1, b_u,
                                                     random_w, conv_w1, conv_b1,
                                                     conv_w2, conv_b2, conv_w3,
                                                     conv_b3, outp, wsp);
    k3_out<<<(NBB*NGG)/16, 256, 0, stream>>>(bn_gamma, bn_beta, g_w, g_b, outp, wsp);
}